// Round 1
// baseline (211.287 us; speedup 1.0000x reference)
//
#include <hip/hip_runtime.h>

typedef __attribute__((ext_vector_type(4))) float f32x4;
typedef __attribute__((ext_vector_type(8))) short short8;
typedef __attribute__((ext_vector_type(8))) __bf16 bf16x8;

#define NB 4
#define NS 2048
#define NHID 576
#define NHEADS 9
#define NKVH 3
#define NHD 64
#define NM (NB * NS)      // 8192 rows
#define NQKV 960          // (9 + 3 + 3) * 64
#define NGRP 3            // NHEADS / NKVH

static __device__ __forceinline__ unsigned short f2bf(float f) {
  union { float f; unsigned u; } v; v.f = f;
  unsigned r = v.u + 0x7FFFu + ((v.u >> 16) & 1u);
  return (unsigned short)(r >> 16);
}
static __device__ __forceinline__ float bf2f(unsigned short h) {
  union { unsigned u; float f; } v; v.u = ((unsigned)h) << 16;
  return v.f;
}
static __device__ __forceinline__ f32x4 mfma16(short8 a, short8 b, f32x4 c) {
  return __builtin_amdgcn_mfma_f32_16x16x32_bf16(
      __builtin_bit_cast(bf16x8, a), __builtin_bit_cast(bf16x8, b), c, 0, 0, 0);
}
static __device__ __forceinline__ void gload16(const void* g, void* l) {
  __builtin_amdgcn_global_load_lds(
      (const __attribute__((address_space(1))) void*)g,
      (__attribute__((address_space(3))) void*)l, 16, 0, 0);
}

// ---------------- f32 -> bf16 convert (x) ----------------
__global__ __launch_bounds__(256)
void k_cvt(const float* __restrict__ src, unsigned short* __restrict__ dst, const int n8) {
  const int t = blockIdx.x * 256 + threadIdx.x;
  if (t >= n8) return;
  const f32x4* sp = (const f32x4*)(src + (size_t)t * 8);
  f32x4 a = sp[0], b = sp[1];
  union { short8 v; unsigned short u[8]; } o;
#pragma unroll
  for (int e = 0; e < 4; ++e) { o.u[e] = f2bf(a[e]); o.u[4 + e] = f2bf(b[e]); }
  *(short8*)(dst + (size_t)t * 8) = o.v;
}

// ---------------- transpose + convert: src[R][C] f32 -> dst[c][r] bf16 (row stride R) ----------------
__global__ __launch_bounds__(256)
void k_transpose_cvt(const float* __restrict__ src, unsigned short* __restrict__ dst,
                     const int R, const int C) {
  __shared__ unsigned short tile[64 * 72];
  const int t = threadIdx.x;
  const int r0 = blockIdx.y * 64, c0 = blockIdx.x * 64;
  {
    const int rl = t >> 2, cb = (t & 3) * 16;
    const float* sp = src + (size_t)(r0 + rl) * C + c0 + cb;
#pragma unroll
    for (int jj = 0; jj < 4; ++jj) {
      f32x4 v = *(const f32x4*)(sp + jj * 4);
#pragma unroll
      for (int e = 0; e < 4; ++e) tile[rl * 72 + cb + jj * 4 + e] = f2bf(v[e]);
    }
  }
  __syncthreads();
  {
    const int cl = t >> 2, rb = (t & 3) * 16;
    union { short8 v; unsigned short u[8]; } o0, o1;
#pragma unroll
    for (int jj = 0; jj < 8; ++jj) {
      o0.u[jj] = tile[(rb + jj) * 72 + cl];
      o1.u[jj] = tile[(rb + 8 + jj) * 72 + cl];
    }
    unsigned short* dp = dst + (size_t)(c0 + cl) * R + r0 + rb;
    *(short8*)dp = o0.v;
    *(short8*)(dp + 8) = o1.v;
  }
}

// ---------------- GEMM: C[M][N] = A[M][K](bf16) * Bt[N][K](bf16)^T ----------------
// BM=128 BN=64 BK=64, 4 waves, global_load_lds staging, XOR-swizzled LDS.
template <int OUT_F32>
__global__ __launch_bounds__(256)
void k_gemm_bt(const unsigned short* __restrict__ A,
               const unsigned short* __restrict__ Bt,
               void* __restrict__ Cv,
               const int M, const int N, const int K) {
  __shared__ unsigned short a_lds[128 * 64];  // 16 KB
  __shared__ unsigned short b_lds[64 * 64];   // 8 KB
  const int tid = threadIdx.x;
  const int w = tid >> 6, l = tid & 63, g = l >> 4, c = l & 15;
  const int tm = blockIdx.y * 128, tn = blockIdx.x * 64;
  const int wm = w >> 1, wn = w & 1;
  f32x4 acc[4][2] = {};

  for (int k0 = 0; k0 < K; k0 += 64) {
#pragma unroll
    for (int q = 0; q < 4; ++q) {
      const int o = q * 4096 + w * 1024 + l * 16;     // byte slot in 16KB A tile
      const int row = o >> 7;                          // 128B per row (BK=64 bf16)
      const int wb = (o & 127) ^ ((row & 7) << 4);     // pre-swizzled source column byte
      gload16(A + (size_t)(tm + row) * K + k0 + (wb >> 1),
              (void*)(a_lds + ((q * 4096 + w * 1024) >> 1)));
    }
#pragma unroll
    for (int q = 0; q < 2; ++q) {
      const int o = q * 4096 + w * 1024 + l * 16;
      const int row = o >> 7;
      const int wb = (o & 127) ^ ((row & 7) << 4);
      gload16(Bt + (size_t)(tn + row) * K + k0 + (wb >> 1),
              (void*)(b_lds + ((q * 4096 + w * 1024) >> 1)));
    }
    __syncthreads();
#pragma unroll
    for (int dc = 0; dc < 2; ++dc) {
      short8 af[4], bf[2];
#pragma unroll
      for (int mt = 0; mt < 4; ++mt) {
        const int row = wm * 64 + mt * 16 + c;
        const int byt = ((row << 7) + (dc << 6) + (g << 4)) ^ ((row & 7) << 4);
        af[mt] = *(const short8*)((const char*)a_lds + byt);
      }
#pragma unroll
      for (int nt = 0; nt < 2; ++nt) {
        const int row = wn * 32 + nt * 16 + c;
        const int byt = ((row << 7) + (dc << 6) + (g << 4)) ^ ((row & 7) << 4);
        bf[nt] = *(const short8*)((const char*)b_lds + byt);
      }
#pragma unroll
      for (int mt = 0; mt < 4; ++mt)
#pragma unroll
        for (int nt = 0; nt < 2; ++nt)
          acc[mt][nt] = mfma16(af[mt], bf[nt], acc[mt][nt]);
    }
    __syncthreads();
  }

#pragma unroll
  for (int mt = 0; mt < 4; ++mt)
#pragma unroll
    for (int nt = 0; nt < 2; ++nt)
#pragma unroll
      for (int i = 0; i < 4; ++i) {
        const size_t rr = (size_t)(tm + wm * 64 + mt * 16 + 4 * g + i);
        const size_t cc = (size_t)(tn + wn * 32 + nt * 16 + c);
        if (OUT_F32) ((float*)Cv)[rr * N + cc] = acc[mt][nt][i];
        else ((unsigned short*)Cv)[rr * N + cc] = f2bf(acc[mt][nt][i]);
      }
}

// ---------------- RoPE in-place on q,k (cols 0..767 of qkv) ----------------
__global__ __launch_bounds__(256)
void k_rope(unsigned short* __restrict__ qkv, const float* __restrict__ cosT,
            const float* __restrict__ sinT) {
  const int t = blockIdx.x * 256 + threadIdx.x;  // NM*48 threads
  const int m = t / 48, r = t - m * 48;
  const int hc = r >> 2, qq = r & 3;   // head-col 0..11, quarter 0..3
  const int s = m & (NS - 1);
  unsigned short* p = qkv + (size_t)m * NQKV + hc * NHD + qq * 8;
  short8 x1 = *(short8*)p;
  short8 x2 = *(short8*)(p + 32);
  const float* cp = cosT + s * NHD + qq * 8;
  const float* sp = sinT + s * NHD + qq * 8;
  f32x4 c0 = *(const f32x4*)cp, c1 = *(const f32x4*)(cp + 4);
  f32x4 s0 = *(const f32x4*)sp, s1 = *(const f32x4*)(sp + 4);
  float cc[8] = {c0[0], c0[1], c0[2], c0[3], c1[0], c1[1], c1[2], c1[3]};
  float ss[8] = {s0[0], s0[1], s0[2], s0[3], s1[0], s1[1], s1[2], s1[3]};
  union { short8 v; unsigned short u[8]; } o1, o2;
#pragma unroll
  for (int jj = 0; jj < 8; ++jj) {
    float a = bf2f((unsigned short)x1[jj]);
    float bb = bf2f((unsigned short)x2[jj]);
    o1.u[jj] = f2bf(a * cc[jj] - bb * ss[jj]);
    o2.u[jj] = f2bf(bb * cc[jj] + a * ss[jj]);
  }
  *(short8*)p = o1.v;
  *(short8*)(p + 32) = o2.v;
}

// ---------------- V^T precompute: vt[(b*NKVH+kh)][d][s] = v ----------------
__global__ __launch_bounds__(256)
void k_vt(const unsigned short* __restrict__ qkv, unsigned short* __restrict__ vt) {
  __shared__ unsigned short tile[64 * 72];
  const int t = threadIdx.x;
  const int st = blockIdx.x;           // s-tile 0..31
  const int by = blockIdx.y;           // b*NKVH + kh
  const int b = by / NKVH, kh = by - b * NKVH;
  {
    const int sl2 = t >> 2, d0 = (t & 3) * 16;
    const unsigned short* sp = qkv + (size_t)(b * NS + st * 64 + sl2) * NQKV +
                               (NHEADS + NKVH) * NHD + kh * NHD + d0;
    *(short8*)&tile[sl2 * 72 + d0] = *(const short8*)sp;
    *(short8*)&tile[sl2 * 72 + d0 + 8] = *(const short8*)(sp + 8);
  }
  __syncthreads();
  {
    const int dl = t >> 2, s0 = (t & 3) * 16;
    union { short8 v; unsigned short u[8]; } o0, o1;
#pragma unroll
    for (int jj = 0; jj < 8; ++jj) {
      o0.u[jj] = tile[(s0 + jj) * 72 + dl];
      o1.u[jj] = tile[(s0 + 8 + jj) * 72 + dl];
    }
    unsigned short* dp = vt + (size_t)(by * 64 + dl) * NS + st * 64 + s0;
    *(short8*)dp = o0.v;
    *(short8*)(dp + 8) = o1.v;
  }
}

// ---------------- causal GQA flash attention ----------------
// block = (qt, b*NHEADS+h): 64 q-rows, 4 waves x 16 rows. KV tiles of 64.
#define KP 72
__global__ __launch_bounds__(256)
void k_attn(const unsigned short* __restrict__ qkv,
            const unsigned short* __restrict__ vt,
            unsigned short* __restrict__ ao) {
  __shared__ unsigned short k_lds[64 * KP];
  __shared__ unsigned short v_lds[64 * KP];      // V^T tile: [d][kv]
  __shared__ unsigned short p_lds[4][16 * KP];   // per-wave P scratch
  const int tid = threadIdx.x;
  const int w = tid >> 6, l = tid & 63, g = l >> 4, c = l & 15;
  const int qt = blockIdx.x;
  const int bh = blockIdx.y;
  const int b = bh / NHEADS, h = bh - b * NHEADS, kh = h / NGRP;

  // Q fragments (A-operand): lane holds Q[row=c][d = dc*32 + 8g .. +7]
  const size_t qrow = (size_t)(b * NS + qt * 64 + w * 16 + c) * NQKV + h * NHD;
  const short8 qf0 = *(const short8*)(qkv + qrow + g * 8);
  const short8 qf1 = *(const short8*)(qkv + qrow + 32 + g * 8);

  f32x4 oa0 = {0, 0, 0, 0}, oa1 = {0, 0, 0, 0}, oa2 = {0, 0, 0, 0}, oa3 = {0, 0, 0, 0};
  float mrow[4] = {-1e30f, -1e30f, -1e30f, -1e30f};
  float lrow[4] = {0.f, 0.f, 0.f, 0.f};

  const unsigned short* kbase = qkv + (size_t)b * NS * NQKV + NHEADS * NHD + kh * NHD;
  const unsigned short* vbase = vt + (size_t)(b * NKVH + kh) * NHD * NS;

  const int sl = tid >> 2;         // staging row 0..63
  const int sb = (tid & 3) * 16;   // staging 16-elem chunk

  for (int j = 0; j <= qt; ++j) {
    {  // stage K tile [kv][d] and V^T tile [d][kv]
      const unsigned short* kp = kbase + (size_t)(j * 64 + sl) * NQKV + sb;
      short8 a0 = *(const short8*)kp;
      short8 a1 = *(const short8*)(kp + 8);
      const unsigned short* vp = vbase + (size_t)sl * NS + j * 64 + sb;
      short8 b0 = *(const short8*)vp;
      short8 b1 = *(const short8*)(vp + 8);
      *(short8*)&k_lds[sl * KP + sb] = a0;
      *(short8*)&k_lds[sl * KP + sb + 8] = a1;
      *(short8*)&v_lds[sl * KP + sb] = b0;
      *(short8*)&v_lds[sl * KP + sb + 8] = b1;
    }
    __syncthreads();

    // S = Q K^T  (16q x 64kv per wave)
    f32x4 sa[4] = {{0,0,0,0},{0,0,0,0},{0,0,0,0},{0,0,0,0}};
#pragma unroll
    for (int nt = 0; nt < 4; ++nt) {
      short8 kf0 = *(const short8*)&k_lds[(nt * 16 + c) * KP + g * 8];
      short8 kf1 = *(const short8*)&k_lds[(nt * 16 + c) * KP + 32 + g * 8];
      sa[nt] = mfma16(qf0, kf0, sa[nt]);
      sa[nt] = mfma16(qf1, kf1, sa[nt]);
    }

    // scale + causal mask (tile j == qt straddles the diagonal)
#pragma unroll
    for (int nt = 0; nt < 4; ++nt)
#pragma unroll
      for (int i = 0; i < 4; ++i) {
        float v = sa[nt][i] * 0.125f;
        if (j == qt && (nt * 16 + c) > (w * 16 + 4 * g + i)) v = -1e30f;
        sa[nt][i] = v;
      }

    // online softmax: rows live in 16-lane groups (row = 4g+i, col = c)
    float rmax[4], rsum[4], pv[4][4];
#pragma unroll
    for (int i = 0; i < 4; ++i)
      rmax[i] = fmaxf(fmaxf(sa[0][i], sa[1][i]), fmaxf(sa[2][i], sa[3][i]));
#pragma unroll
    for (int off = 1; off < 16; off <<= 1)
#pragma unroll
      for (int i = 0; i < 4; ++i)
        rmax[i] = fmaxf(rmax[i], __shfl_xor(rmax[i], off));

#pragma unroll
    for (int i = 0; i < 4; ++i) {
      float mn = fmaxf(mrow[i], rmax[i]);
      float scl = __expf(mrow[i] - mn);
      mrow[i] = mn;
      lrow[i] *= scl;
      oa0[i] = oa0[i] * scl; oa1[i] = oa1[i] * scl;
      oa2[i] = oa2[i] * scl; oa3[i] = oa3[i] * scl;
#pragma unroll
      for (int nt = 0; nt < 4; ++nt) pv[nt][i] = __expf(sa[nt][i] - mn);
    }
#pragma unroll
    for (int i = 0; i < 4; ++i)
      rsum[i] = pv[0][i] + pv[1][i] + pv[2][i] + pv[3][i];
#pragma unroll
    for (int off = 1; off < 16; off <<= 1)
#pragma unroll
      for (int i = 0; i < 4; ++i)
        rsum[i] += __shfl_xor(rsum[i], off);
#pragma unroll
    for (int i = 0; i < 4; ++i) lrow[i] += rsum[i];

    // P -> bf16 via per-wave LDS transpose (same-wave write->read, no barrier needed)
#pragma unroll
    for (int nt = 0; nt < 4; ++nt)
#pragma unroll
      for (int i = 0; i < 4; ++i)
        p_lds[w][(4 * g + i) * KP + nt * 16 + c] = f2bf(pv[nt][i]);

    // O += P V  (A = P from p_lds, B = V from v_lds^T rows)
#pragma unroll
    for (int dc = 0; dc < 2; ++dc) {
      short8 pf = *(const short8*)&p_lds[w][c * KP + dc * 32 + g * 8];
      short8 vf0 = *(const short8*)&v_lds[(0 * 16 + c) * KP + dc * 32 + g * 8];
      short8 vf1 = *(const short8*)&v_lds[(1 * 16 + c) * KP + dc * 32 + g * 8];
      short8 vf2 = *(const short8*)&v_lds[(2 * 16 + c) * KP + dc * 32 + g * 8];
      short8 vf3 = *(const short8*)&v_lds[(3 * 16 + c) * KP + dc * 32 + g * 8];
      oa0 = mfma16(pf, vf0, oa0);
      oa1 = mfma16(pf, vf1, oa1);
      oa2 = mfma16(pf, vf2, oa2);
      oa3 = mfma16(pf, vf3, oa3);
    }
    __syncthreads();
  }

#pragma unroll
  for (int i = 0; i < 4; ++i) {
    const size_t rr = (size_t)(b * NS + qt * 64 + w * 16 + 4 * g + i) * (NHEADS * NHD) + h * NHD;
    const float inv = 1.0f / lrow[i];
    ao[rr + 0 + c] = f2bf(oa0[i] * inv);
    ao[rr + 16 + c] = f2bf(oa1[i] * inv);
    ao[rr + 32 + c] = f2bf(oa2[i] * inv);
    ao[rr + 48 + c] = f2bf(oa3[i] * inv);
  }
}

extern "C" void kernel_launch(void* const* d_in, const int* in_sizes, int n_in,
                              void* d_out, int out_size, void* d_ws, size_t ws_size,
                              hipStream_t stream) {
  const float* x = (const float*)d_in[0];
  const float* cosT = (const float*)d_in[1];
  const float* sinT = (const float*)d_in[2];
  // d_in[3] = mask (unused; causal handled analytically)
  const float* Wq = (const float*)d_in[4];
  const float* Wk = (const float*)d_in[5];
  const float* Wv = (const float*)d_in[6];
  const float* Wo = (const float*)d_in[7];

  // workspace layout (bf16), ~39.5 MB total
  unsigned short* xb = (unsigned short*)d_ws;                      // [8192][576]
  unsigned short* wqkvT = xb + (size_t)NM * NHID;                  // [960][576]
  unsigned short* woT = wqkvT + (size_t)NQKV * NHID;               // [576][576]
  unsigned short* qkv = woT + (size_t)NHID * NHID;                 // [8192][960]
  unsigned short* vt = qkv + (size_t)NM * NQKV;                    // [12][64][2048]
  unsigned short* ao = vt + (size_t)NB * NKVH * NHD * NS;          // [8192][576]

  k_cvt<<<dim3((NM * NHID / 8 + 255) / 256), 256, 0, stream>>>(x, xb, NM * NHID / 8);
  k_transpose_cvt<<<dim3(9, 9), 256, 0, stream>>>(Wq, wqkvT, NHID, NHID);
  k_transpose_cvt<<<dim3(3, 9), 256, 0, stream>>>(Wk, wqkvT + (size_t)576 * 576, NHID, 192);
  k_transpose_cvt<<<dim3(3, 9), 256, 0, stream>>>(Wv, wqkvT + (size_t)768 * 576, NHID, 192);
  k_transpose_cvt<<<dim3(9, 9), 256, 0, stream>>>(Wo, woT, NHID, NHID);
  k_gemm_bt<0><<<dim3(NQKV / 64, NM / 128), 256, 0, stream>>>(xb, wqkvT, (void*)qkv, NM, NQKV, NHID);
  k_rope<<<dim3(NM * 48 / 256), 256, 0, stream>>>(qkv, cosT, sinT);
  k_vt<<<dim3(NS / 64, NB * NKVH), 256, 0, stream>>>(qkv, vt);
  k_attn<<<dim3(NS / 64, NB * NHEADS), 256, 0, stream>>>(qkv, vt, ao);
  k_gemm_bt<1><<<dim3(NHID / 64, NM / 128), 256, 0, stream>>>(ao, woT, d_out, NM, NHID, NHID);
}

// Round 2
// 115.775 us; speedup vs baseline: 1.8250x; 1.8250x over previous
//
#include <hip/hip_runtime.h>

typedef __attribute__((ext_vector_type(4))) float f32x4;
typedef __attribute__((ext_vector_type(8))) short short8;
typedef __attribute__((ext_vector_type(8))) __bf16 bf16x8;
typedef __attribute__((ext_vector_type(2))) unsigned uint32x2;

#define NB 4
#define NS 2048
#define NHID 576
#define NHEADS 9
#define NKVH 3
#define NHD 64
#define NM (NB * NS)      // 8192 rows
#define NQKV 960          // (9 + 3 + 3) * 64
#define NGRP 3            // NHEADS / NKVH

static __device__ __forceinline__ unsigned short f2bf(float f) {
  union { float f; unsigned u; } v; v.f = f;
  unsigned r = v.u + 0x7FFFu + ((v.u >> 16) & 1u);
  return (unsigned short)(r >> 16);
}
static __device__ __forceinline__ float bf2f(unsigned short h) {
  union { unsigned u; float f; } v; v.u = ((unsigned)h) << 16;
  return v.f;
}
static __device__ __forceinline__ f32x4 mfma16(short8 a, short8 b, f32x4 c) {
  return __builtin_amdgcn_mfma_f32_16x16x32_bf16(
      __builtin_bit_cast(bf16x8, a), __builtin_bit_cast(bf16x8, b), c, 0, 0, 0);
}
static __device__ __forceinline__ void gload16(const void* g, void* l) {
  __builtin_amdgcn_global_load_lds(
      (const __attribute__((address_space(1))) void*)g,
      (__attribute__((address_space(3))) void*)l, 16, 0, 0);
}

// ---------------- f32 -> bf16 convert (x) ----------------
__global__ __launch_bounds__(256)
void k_cvt(const float* __restrict__ src, unsigned short* __restrict__ dst, const int n8) {
  const int t = blockIdx.x * 256 + threadIdx.x;
  if (t >= n8) return;
  const f32x4* sp = (const f32x4*)(src + (size_t)t * 8);
  f32x4 a = sp[0], b = sp[1];
  union { short8 v; unsigned short u[8]; } o;
#pragma unroll
  for (int e = 0; e < 4; ++e) { o.u[e] = f2bf(a[e]); o.u[4 + e] = f2bf(b[e]); }
  *(short8*)(dst + (size_t)t * 8) = o.v;
}

// ---------------- transpose + convert: src[R][C] f32 -> dst[c][r] bf16 ----------------
__global__ __launch_bounds__(256)
void k_transpose_cvt(const float* __restrict__ src, unsigned short* __restrict__ dst,
                     const int R, const int C) {
  __shared__ unsigned short tile[64 * 72];
  const int t = threadIdx.x;
  const int r0 = blockIdx.y * 64, c0 = blockIdx.x * 64;
  {
    const int rl = t >> 2, cb = (t & 3) * 16;
    const float* sp = src + (size_t)(r0 + rl) * C + c0 + cb;
#pragma unroll
    for (int jj = 0; jj < 4; ++jj) {
      f32x4 v = *(const f32x4*)(sp + jj * 4);
#pragma unroll
      for (int e = 0; e < 4; ++e) tile[rl * 72 + cb + jj * 4 + e] = f2bf(v[e]);
    }
  }
  __syncthreads();
  {
    const int cl = t >> 2, rb = (t & 3) * 16;
    union { short8 v; unsigned short u[8]; } o0, o1;
#pragma unroll
    for (int jj = 0; jj < 8; ++jj) {
      o0.u[jj] = tile[(rb + jj) * 72 + cl];
      o1.u[jj] = tile[(rb + 8 + jj) * 72 + cl];
    }
    unsigned short* dp = dst + (size_t)(c0 + cl) * R + r0 + rb;
    *(short8*)dp = o0.v;
    *(short8*)(dp + 8) = o1.v;
  }
}

// ---------------- GEMM: C[M][N] = A[M][K](bf16) * Bt[N][K](bf16)^T ----------------
template <int OUT_F32>
__global__ __launch_bounds__(256)
void k_gemm_bt(const unsigned short* __restrict__ A,
               const unsigned short* __restrict__ Bt,
               void* __restrict__ Cv,
               const int M, const int N, const int K) {
  __shared__ unsigned short a_lds[128 * 64];
  __shared__ unsigned short b_lds[64 * 64];
  const int tid = threadIdx.x;
  const int w = tid >> 6, l = tid & 63, g = l >> 4, c = l & 15;
  const int tm = blockIdx.y * 128, tn = blockIdx.x * 64;
  const int wm = w >> 1, wn = w & 1;
  f32x4 acc[4][2] = {};

  for (int k0 = 0; k0 < K; k0 += 64) {
#pragma unroll
    for (int q = 0; q < 4; ++q) {
      const int o = q * 4096 + w * 1024 + l * 16;
      const int row = o >> 7;
      const int wb = (o & 127) ^ ((row & 7) << 4);
      gload16(A + (size_t)(tm + row) * K + k0 + (wb >> 1),
              (void*)(a_lds + ((q * 4096 + w * 1024) >> 1)));
    }
#pragma unroll
    for (int q = 0; q < 2; ++q) {
      const int o = q * 4096 + w * 1024 + l * 16;
      const int row = o >> 7;
      const int wb = (o & 127) ^ ((row & 7) << 4);
      gload16(Bt + (size_t)(tn + row) * K + k0 + (wb >> 1),
              (void*)(b_lds + ((q * 4096 + w * 1024) >> 1)));
    }
    __syncthreads();
#pragma unroll
    for (int dc = 0; dc < 2; ++dc) {
      short8 af[4], bf[2];
#pragma unroll
      for (int mt = 0; mt < 4; ++mt) {
        const int row = wm * 64 + mt * 16 + c;
        const int byt = ((row << 7) + (dc << 6) + (g << 4)) ^ ((row & 7) << 4);
        af[mt] = *(const short8*)((const char*)a_lds + byt);
      }
#pragma unroll
      for (int nt = 0; nt < 2; ++nt) {
        const int row = wn * 32 + nt * 16 + c;
        const int byt = ((row << 7) + (dc << 6) + (g << 4)) ^ ((row & 7) << 4);
        bf[nt] = *(const short8*)((const char*)b_lds + byt);
      }
#pragma unroll
      for (int mt = 0; mt < 4; ++mt)
#pragma unroll
        for (int nt = 0; nt < 2; ++nt)
          acc[mt][nt] = mfma16(af[mt], bf[nt], acc[mt][nt]);
    }
    __syncthreads();
  }

#pragma unroll
  for (int mt = 0; mt < 4; ++mt)
#pragma unroll
    for (int nt = 0; nt < 2; ++nt)
#pragma unroll
      for (int i = 0; i < 4; ++i) {
        const size_t rr = (size_t)(tm + wm * 64 + mt * 16 + 4 * g + i);
        const size_t cc = (size_t)(tn + wn * 32 + nt * 16 + c);
        if (OUT_F32) ((float*)Cv)[rr * N + cc] = acc[mt][nt][i];
        else ((unsigned short*)Cv)[rr * N + cc] = f2bf(acc[mt][nt][i]);
      }
}

// ---------------- RoPE in-place on q,k; q additionally scaled by 1/sqrt(HD) ----------------
__global__ __launch_bounds__(256)
void k_rope(unsigned short* __restrict__ qkv, const float* __restrict__ cosT,
            const float* __restrict__ sinT) {
  const int t = blockIdx.x * 256 + threadIdx.x;
  const int m = t / 48, r = t - m * 48;
  const int hc = r >> 2, qq = r & 3;
  const int s = m & (NS - 1);
  const float qs = (hc < NHEADS) ? 0.125f : 1.0f;
  unsigned short* p = qkv + (size_t)m * NQKV + hc * NHD + qq * 8;
  short8 x1 = *(short8*)p;
  short8 x2 = *(short8*)(p + 32);
  const float* cp = cosT + s * NHD + qq * 8;
  const float* sp = sinT + s * NHD + qq * 8;
  f32x4 c0 = *(const f32x4*)cp, c1 = *(const f32x4*)(cp + 4);
  f32x4 s0 = *(const f32x4*)sp, s1 = *(const f32x4*)(sp + 4);
  float cc[8] = {c0[0], c0[1], c0[2], c0[3], c1[0], c1[1], c1[2], c1[3]};
  float ss[8] = {s0[0], s0[1], s0[2], s0[3], s1[0], s1[1], s1[2], s1[3]};
  union { short8 v; unsigned short u[8]; } o1, o2;
#pragma unroll
  for (int jj = 0; jj < 8; ++jj) {
    float a = bf2f((unsigned short)x1[jj]);
    float bb = bf2f((unsigned short)x2[jj]);
    o1.u[jj] = f2bf((a * cc[jj] - bb * ss[jj]) * qs);
    o2.u[jj] = f2bf((bb * cc[jj] + a * ss[jj]) * qs);
  }
  *(short8*)p = o1.v;
  *(short8*)(p + 32) = o2.v;
}

// ---------------- V^T precompute: vt[(b*NKVH+kh)][d][s] ----------------
__global__ __launch_bounds__(256)
void k_vt(const unsigned short* __restrict__ qkv, unsigned short* __restrict__ vt) {
  __shared__ unsigned short tile[64 * 72];
  const int t = threadIdx.x;
  const int st = blockIdx.x;
  const int by = blockIdx.y;
  const int b = by / NKVH, kh = by - b * NKVH;
  {
    const int sl2 = t >> 2, d0 = (t & 3) * 16;
    const unsigned short* sp = qkv + (size_t)(b * NS + st * 64 + sl2) * NQKV +
                               (NHEADS + NKVH) * NHD + kh * NHD + d0;
    *(short8*)&tile[sl2 * 72 + d0] = *(const short8*)sp;
    *(short8*)&tile[sl2 * 72 + d0 + 8] = *(const short8*)(sp + 8);
  }
  __syncthreads();
  {
    const int dl = t >> 2, s0 = (t & 3) * 16;
    union { short8 v; unsigned short u[8]; } o0, o1;
#pragma unroll
    for (int jj = 0; jj < 8; ++jj) {
      o0.u[jj] = tile[(s0 + jj) * 72 + dl];
      o1.u[jj] = tile[(s0 + 8 + jj) * 72 + dl];
    }
    unsigned short* dp = vt + (size_t)(by * 64 + dl) * NS + st * 64 + s0;
    *(short8*)dp = o0.v;
    *(short8*)(dp + 8) = o1.v;
  }
}

// ---------------- causal GQA flash attention (swapped-operand, double-buffered) ----------------
// grid = (36 bh, 32 qtIdx), qt = 31 - qtIdx (longest-first). 4 waves x 16 q-rows.
// All LDS tiles XOR-swizzled: physical_byte = logical_byte ^ ((row&7)<<4), row stride 128B.
__global__ __launch_bounds__(256)
void k_attn(const unsigned short* __restrict__ qkv,
            const unsigned short* __restrict__ vt,
            unsigned short* __restrict__ ao) {
  __shared__ unsigned short kv_s[2][2][4096];   // [half][K=0/V=1][64 rows x 64]
  __shared__ unsigned short p_s[4][1024];       // per-wave P^T [16 q][64 kv]
  const int tid = threadIdx.x;
  const int w = tid >> 6, l = tid & 63, g = l >> 4, c = l & 15;
  const int bh = blockIdx.x;
  const int qt = 31 - (int)blockIdx.y;
  const int b = bh / NHEADS, h = bh - b * NHEADS, kh = h / NGRP;

  const char* kgb = (const char*)(qkv + (size_t)b * NS * NQKV + NHEADS * NHD + kh * NHD);
  const char* vgb = (const char*)(vt + (size_t)(b * NKVH + kh) * NHD * NS);

  const int lr = l >> 3;                     // 0..7
  const int swz = ((l & 7) ^ lr) << 4;       // pre-swizzled source column byte
  const int r0 = 16 * w + lr;                // this lane's staging row (and +8)
  const int cs = (c & 7) << 4;               // read-side XOR key

  // Q fragments (B-operand): lane holds Q[q=w*16+c][d = dc*32 + g*8 + j] (pre-scaled by 1/8)
  const size_t qrow = (size_t)(b * NS + qt * 64 + w * 16 + c) * NQKV + h * NHD;
  const short8 qf0 = *(const short8*)(qkv + qrow + g * 8);
  const short8 qf1 = *(const short8*)(qkv + qrow + 32 + g * 8);

  f32x4 ot[4] = {};            // O^T: lane holds O^T[d=nt*16+4g+i][q=w*16+c]
  float m = -1e30f, lsum = 0.f;
  const int q_g = qt * 64 + w * 16 + c;

  // stage KV tile j into buffer half: 4 x global_load_lds per wave
#define STAGE(j, half)                                                          \
  {                                                                             \
    unsigned short* kl_ = kv_s[half][0];                                        \
    unsigned short* vl_ = kv_s[half][1];                                        \
    gload16(kgb + (size_t)((j) * 64 + r0) * (NQKV * 2) + swz, kl_ + 16 * w * 64);       \
    gload16(kgb + (size_t)((j) * 64 + r0 + 8) * (NQKV * 2) + swz, kl_ + (16 * w + 8) * 64); \
    gload16(vgb + (size_t)r0 * (NS * 2) + (j) * 128 + swz, vl_ + 16 * w * 64);          \
    gload16(vgb + (size_t)(r0 + 8) * (NS * 2) + (j) * 128 + swz, vl_ + (16 * w + 8) * 64); \
  }

  STAGE(0, 0);

  for (int j = 0; j <= qt; ++j) {
    __syncthreads();                     // drains tile-j loads; all waves past reads of buf (j-1)
    if (j < qt) STAGE(j + 1, (j + 1) & 1);
    const char* kl = (const char*)kv_s[j & 1][0];
    const char* vl = (const char*)kv_s[j & 1][1];

    // S^T = K Q^T : per nt sub-tile, lane holds S^T[kv=j*64+nt*16+4g+i][q=c]
    f32x4 st[4] = {};
#pragma unroll
    for (int dc = 0; dc < 2; ++dc) {
      const int col = (dc * 64 + g * 16) ^ cs;
      const short8 qf = dc ? qf1 : qf0;
#pragma unroll
      for (int nt = 0; nt < 4; ++nt) {
        short8 kf = *(const short8*)(kl + (nt * 16 + c) * 128 + col);
        st[nt] = mfma16(kf, qf, st[nt]);
      }
    }

    // causal mask
#pragma unroll
    for (int nt = 0; nt < 4; ++nt)
#pragma unroll
      for (int i = 0; i < 4; ++i) {
        const int kvg = j * 64 + nt * 16 + 4 * g + i;
        if (kvg > q_g) st[nt][i] = -1e30f;
      }

    // softmax (per lane = one q column): in-lane max tree + 2 shfl
    float t0 = fmaxf(fmaxf(st[0][0], st[0][1]), fmaxf(st[0][2], st[0][3]));
    float t1 = fmaxf(fmaxf(st[1][0], st[1][1]), fmaxf(st[1][2], st[1][3]));
    float t2 = fmaxf(fmaxf(st[2][0], st[2][1]), fmaxf(st[2][2], st[2][3]));
    float t3 = fmaxf(fmaxf(st[3][0], st[3][1]), fmaxf(st[3][2], st[3][3]));
    float pm = fmaxf(fmaxf(t0, t1), fmaxf(t2, t3));
    pm = fmaxf(pm, __shfl_xor(pm, 16));
    pm = fmaxf(pm, __shfl_xor(pm, 32));

    const float mn = fmaxf(m, pm);
    const float scl = __expf(m - mn);
    m = mn;
    float pv[4][4];
    float rs = 0.f;
#pragma unroll
    for (int nt = 0; nt < 4; ++nt)
#pragma unroll
      for (int i = 0; i < 4; ++i) {
        pv[nt][i] = __expf(st[nt][i] - mn);
        rs += pv[nt][i];
      }
    rs += __shfl_xor(rs, 16);
    rs += __shfl_xor(rs, 32);
    lsum = lsum * scl + rs;
#pragma unroll
    for (int nt = 0; nt < 4; ++nt)
#pragma unroll
      for (int i = 0; i < 4; ++i) ot[nt][i] *= scl;

    // P^T -> per-wave LDS, packed b64 writes (same-wave write->read)
    {
      char* pw = (char*)p_s[w];
#pragma unroll
      for (int nt = 0; nt < 4; ++nt) {
        uint32x2 pk;
        pk.x = (unsigned)f2bf(pv[nt][0]) | ((unsigned)f2bf(pv[nt][1]) << 16);
        pk.y = (unsigned)f2bf(pv[nt][2]) | ((unsigned)f2bf(pv[nt][3]) << 16);
        *(uint32x2*)(pw + c * 128 + ((nt * 32 + g * 8) ^ cs)) = pk;
      }
      // O^T += V^T P^T
#pragma unroll
      for (int dc = 0; dc < 2; ++dc) {
        const int col = (dc * 64 + g * 16) ^ cs;
        short8 pf = *(const short8*)(pw + c * 128 + col);
#pragma unroll
        for (int nt = 0; nt < 4; ++nt) {
          short8 vf = *(const short8*)(vl + (nt * 16 + c) * 128 + col);
          ot[nt] = mfma16(vf, pf, ot[nt]);
        }
      }
    }
  }

  // O^T -> LDS (swizzled) -> coalesced global write
  __syncthreads();
  {
    char* ol = (char*)kv_s[0][0];
    const float inv = 1.0f / lsum;
#pragma unroll
    for (int nt = 0; nt < 4; ++nt) {
      uint32x2 pk;
      pk.x = (unsigned)f2bf(ot[nt][0] * inv) | ((unsigned)f2bf(ot[nt][1] * inv) << 16);
      pk.y = (unsigned)f2bf(ot[nt][2] * inv) | ((unsigned)f2bf(ot[nt][3] * inv) << 16);
      *(uint32x2*)(ol + (w * 16 + c) * 128 + ((nt * 32 + g * 8) ^ cs)) = pk;
    }
  }
  __syncthreads();
  {
    const char* ol = (const char*)kv_s[0][0];
    const int rr = tid >> 2, cb = tid & 3;
    const int rk = (rr & 7) << 4;
    short8 v0 = *(const short8*)(ol + rr * 128 + ((cb * 32) ^ rk));
    short8 v1 = *(const short8*)(ol + rr * 128 + ((cb * 32 + 16) ^ rk));
    char* aop = (char*)(ao + (size_t)(b * NS + qt * 64 + rr) * (NHEADS * NHD) + h * NHD + cb * 16);
    *(short8*)aop = v0;
    *(short8*)(aop + 16) = v1;
  }
#undef STAGE
}

extern "C" void kernel_launch(void* const* d_in, const int* in_sizes, int n_in,
                              void* d_out, int out_size, void* d_ws, size_t ws_size,
                              hipStream_t stream) {
  const float* x = (const float*)d_in[0];
  const float* cosT = (const float*)d_in[1];
  const float* sinT = (const float*)d_in[2];
  const float* Wq = (const float*)d_in[4];
  const float* Wk = (const float*)d_in[5];
  const float* Wv = (const float*)d_in[6];
  const float* Wo = (const float*)d_in[7];

  unsigned short* xb = (unsigned short*)d_ws;                      // [8192][576]
  unsigned short* wqkvT = xb + (size_t)NM * NHID;                  // [960][576]
  unsigned short* woT = wqkvT + (size_t)NQKV * NHID;               // [576][576]
  unsigned short* qkv = woT + (size_t)NHID * NHID;                 // [8192][960]
  unsigned short* vt = qkv + (size_t)NM * NQKV;                    // [12][64][2048]
  unsigned short* ao = vt + (size_t)NB * NKVH * NHD * NS;          // [8192][576]

  k_cvt<<<dim3((NM * NHID / 8 + 255) / 256), 256, 0, stream>>>(x, xb, NM * NHID / 8);
  k_transpose_cvt<<<dim3(9, 9), 256, 0, stream>>>(Wq, wqkvT, NHID, NHID);
  k_transpose_cvt<<<dim3(3, 9), 256, 0, stream>>>(Wk, wqkvT + (size_t)576 * 576, NHID, 192);
  k_transpose_cvt<<<dim3(3, 9), 256, 0, stream>>>(Wv, wqkvT + (size_t)768 * 576, NHID, 192);
  k_transpose_cvt<<<dim3(9, 9), 256, 0, stream>>>(Wo, woT, NHID, NHID);
  k_gemm_bt<0><<<dim3(NQKV / 64, NM / 128), 256, 0, stream>>>(xb, wqkvT, (void*)qkv, NM, NQKV, NHID);
  k_rope<<<dim3(NM * 48 / 256), 256, 0, stream>>>(qkv, cosT, sinT);
  k_vt<<<dim3(NS / 64, NB * NKVH), 256, 0, stream>>>(qkv, vt);
  k_attn<<<dim3(NB * NHEADS, NS / 64), 256, 0, stream>>>(qkv, vt, ao);
  k_gemm_bt<1><<<dim3(NHID / 64, NM / 128), 256, 0, stream>>>(ao, woT, d_out, NM, NHID, NHID);
}

// Round 3
// 111.730 us; speedup vs baseline: 1.8910x; 1.0362x over previous
//
#include <hip/hip_runtime.h>
#include <math.h>

typedef __attribute__((ext_vector_type(4))) float f32x4;
typedef __attribute__((ext_vector_type(8))) short short8;
typedef __attribute__((ext_vector_type(8))) __bf16 bf16x8;
typedef __attribute__((ext_vector_type(2))) __bf16 bf16x2;
typedef __attribute__((ext_vector_type(2))) unsigned uint32x2;

#define NB 4
#define NS 2048
#define NHID 576
#define NHEADS 9
#define NKVH 3
#define NHD 64
#define NM (NB * NS)      // 8192 rows
#define NQKV 960          // (9 + 3 + 3) * 64
#define NGRP 3            // NHEADS / NKVH

static __device__ __forceinline__ unsigned short f2bf(float f) {
  union { float f; unsigned u; } v; v.f = f;
  unsigned r = v.u + 0x7FFFu + ((v.u >> 16) & 1u);
  return (unsigned short)(r >> 16);
}
static __device__ __forceinline__ unsigned pk2bf(float a, float b) {
  bf16x2 h;
  h.x = (__bf16)a;
  h.y = (__bf16)b;
  return __builtin_bit_cast(unsigned, h);
}
static __device__ __forceinline__ float bf2f(unsigned short h) {
  union { unsigned u; float f; } v; v.u = ((unsigned)h) << 16;
  return v.f;
}
static __device__ __forceinline__ f32x4 mfma16(short8 a, short8 b, f32x4 c) {
  return __builtin_amdgcn_mfma_f32_16x16x32_bf16(
      __builtin_bit_cast(bf16x8, a), __builtin_bit_cast(bf16x8, b), c, 0, 0, 0);
}
static __device__ __forceinline__ void gload16(const void* g, void* l) {
  __builtin_amdgcn_global_load_lds(
      (const __attribute__((address_space(1))) void*)g,
      (__attribute__((address_space(3))) void*)l, 16, 0, 0);
}

// ---------------- f32 -> bf16 convert (x) ----------------
__global__ __launch_bounds__(256)
void k_cvt(const float* __restrict__ src, unsigned short* __restrict__ dst, const int n8) {
  const int t = blockIdx.x * 256 + threadIdx.x;
  if (t >= n8) return;
  const f32x4* sp = (const f32x4*)(src + (size_t)t * 8);
  f32x4 a = sp[0], b = sp[1];
  union { short8 v; unsigned short u[8]; } o;
#pragma unroll
  for (int e = 0; e < 4; ++e) { o.u[e] = f2bf(a[e]); o.u[4 + e] = f2bf(b[e]); }
  *(short8*)(dst + (size_t)t * 8) = o.v;
}

// ---------------- transpose + convert: src[R][C] f32 -> dst[c][r] bf16 ----------------
__global__ __launch_bounds__(256)
void k_transpose_cvt(const float* __restrict__ src, unsigned short* __restrict__ dst,
                     const int R, const int C) {
  __shared__ unsigned short tile[64 * 72];
  const int t = threadIdx.x;
  const int r0 = blockIdx.y * 64, c0 = blockIdx.x * 64;
  {
    const int rl = t >> 2, cb = (t & 3) * 16;
    const float* sp = src + (size_t)(r0 + rl) * C + c0 + cb;
#pragma unroll
    for (int jj = 0; jj < 4; ++jj) {
      f32x4 v = *(const f32x4*)(sp + jj * 4);
#pragma unroll
      for (int e = 0; e < 4; ++e) tile[rl * 72 + cb + jj * 4 + e] = f2bf(v[e]);
    }
  }
  __syncthreads();
  {
    const int cl = t >> 2, rb = (t & 3) * 16;
    union { short8 v; unsigned short u[8]; } o0, o1;
#pragma unroll
    for (int jj = 0; jj < 8; ++jj) {
      o0.u[jj] = tile[(rb + jj) * 72 + cl];
      o1.u[jj] = tile[(rb + 8 + jj) * 72 + cl];
    }
    unsigned short* dp = dst + (size_t)(c0 + cl) * R + r0 + rb;
    *(short8*)dp = o0.v;
    *(short8*)(dp + 8) = o1.v;
  }
}

// ---------------- GEMM: C[M][N] = A[M][K](bf16) * Bt[N][K](bf16)^T ----------------
template <int OUT_F32>
__global__ __launch_bounds__(256)
void k_gemm_bt(const unsigned short* __restrict__ A,
               const unsigned short* __restrict__ Bt,
               void* __restrict__ Cv,
               const int M, const int N, const int K) {
  __shared__ unsigned short a_lds[128 * 64];
  __shared__ unsigned short b_lds[64 * 64];
  const int tid = threadIdx.x;
  const int w = tid >> 6, l = tid & 63, g = l >> 4, c = l & 15;
  const int tm = blockIdx.y * 128, tn = blockIdx.x * 64;
  const int wm = w >> 1, wn = w & 1;
  f32x4 acc[4][2] = {};

  for (int k0 = 0; k0 < K; k0 += 64) {
#pragma unroll
    for (int q = 0; q < 4; ++q) {
      const int o = q * 4096 + w * 1024 + l * 16;
      const int row = o >> 7;
      const int wb = (o & 127) ^ ((row & 7) << 4);
      gload16(A + (size_t)(tm + row) * K + k0 + (wb >> 1),
              (void*)(a_lds + ((q * 4096 + w * 1024) >> 1)));
    }
#pragma unroll
    for (int q = 0; q < 2; ++q) {
      const int o = q * 4096 + w * 1024 + l * 16;
      const int row = o >> 7;
      const int wb = (o & 127) ^ ((row & 7) << 4);
      gload16(Bt + (size_t)(tn + row) * K + k0 + (wb >> 1),
              (void*)(b_lds + ((q * 4096 + w * 1024) >> 1)));
    }
    __syncthreads();
#pragma unroll
    for (int dc = 0; dc < 2; ++dc) {
      short8 af[4], bf[2];
#pragma unroll
      for (int mt = 0; mt < 4; ++mt) {
        const int row = wm * 64 + mt * 16 + c;
        const int byt = ((row << 7) + (dc << 6) + (g << 4)) ^ ((row & 7) << 4);
        af[mt] = *(const short8*)((const char*)a_lds + byt);
      }
#pragma unroll
      for (int nt = 0; nt < 2; ++nt) {
        const int row = wn * 32 + nt * 16 + c;
        const int byt = ((row << 7) + (dc << 6) + (g << 4)) ^ ((row & 7) << 4);
        bf[nt] = *(const short8*)((const char*)b_lds + byt);
      }
#pragma unroll
      for (int mt = 0; mt < 4; ++mt)
#pragma unroll
        for (int nt = 0; nt < 2; ++nt)
          acc[mt][nt] = mfma16(af[mt], bf[nt], acc[mt][nt]);
    }
    __syncthreads();
  }

#pragma unroll
  for (int mt = 0; mt < 4; ++mt)
#pragma unroll
    for (int nt = 0; nt < 2; ++nt)
#pragma unroll
      for (int i = 0; i < 4; ++i) {
        const size_t rr = (size_t)(tm + wm * 64 + mt * 16 + 4 * g + i);
        const size_t cc = (size_t)(tn + wn * 32 + nt * 16 + c);
        if (OUT_F32) ((float*)Cv)[rr * N + cc] = acc[mt][nt][i];
        else ((unsigned short*)Cv)[rr * N + cc] = f2bf(acc[mt][nt][i]);
      }
}

// ---------------- RoPE in-place; q scaled by (1/sqrt(HD))*log2(e) for exp2-domain softmax ----------------
__global__ __launch_bounds__(256)
void k_rope(unsigned short* __restrict__ qkv, const float* __restrict__ cosT,
            const float* __restrict__ sinT) {
  const int t = blockIdx.x * 256 + threadIdx.x;
  const int m = t / 48, r = t - m * 48;
  const int hc = r >> 2, qq = r & 3;
  const int s = m & (NS - 1);
  const float qs = (hc < NHEADS) ? 0.18033688f : 1.0f;   // 0.125 * log2(e)
  unsigned short* p = qkv + (size_t)m * NQKV + hc * NHD + qq * 8;
  short8 x1 = *(short8*)p;
  short8 x2 = *(short8*)(p + 32);
  const float* cp = cosT + s * NHD + qq * 8;
  const float* sp = sinT + s * NHD + qq * 8;
  f32x4 c0 = *(const f32x4*)cp, c1 = *(const f32x4*)(cp + 4);
  f32x4 s0 = *(const f32x4*)sp, s1 = *(const f32x4*)(sp + 4);
  float cc[8] = {c0[0], c0[1], c0[2], c0[3], c1[0], c1[1], c1[2], c1[3]};
  float ss[8] = {s0[0], s0[1], s0[2], s0[3], s1[0], s1[1], s1[2], s1[3]};
  union { short8 v; unsigned short u[8]; } o1, o2;
#pragma unroll
  for (int jj = 0; jj < 8; ++jj) {
    float a = bf2f((unsigned short)x1[jj]);
    float bb = bf2f((unsigned short)x2[jj]);
    o1.u[jj] = f2bf((a * cc[jj] - bb * ss[jj]) * qs);
    o2.u[jj] = f2bf((bb * cc[jj] + a * ss[jj]) * qs);
  }
  *(short8*)p = o1.v;
  *(short8*)(p + 32) = o2.v;
}

// ---------------- V^T precompute: vt[(b*NKVH+kh)][d][s] ----------------
__global__ __launch_bounds__(256)
void k_vt(const unsigned short* __restrict__ qkv, unsigned short* __restrict__ vt) {
  __shared__ unsigned short tile[64 * 72];
  const int t = threadIdx.x;
  const int st = blockIdx.x;
  const int by = blockIdx.y;
  const int b = by / NKVH, kh = by - b * NKVH;
  {
    const int sl2 = t >> 2, d0 = (t & 3) * 16;
    const unsigned short* sp = qkv + (size_t)(b * NS + st * 64 + sl2) * NQKV +
                               (NHEADS + NKVH) * NHD + kh * NHD + d0;
    *(short8*)&tile[sl2 * 72 + d0] = *(const short8*)sp;
    *(short8*)&tile[sl2 * 72 + d0 + 8] = *(const short8*)(sp + 8);
  }
  __syncthreads();
  {
    const int dl = t >> 2, s0 = (t & 3) * 16;
    union { short8 v; unsigned short u[8]; } o0, o1;
#pragma unroll
    for (int jj = 0; jj < 8; ++jj) {
      o0.u[jj] = tile[(s0 + jj) * 72 + dl];
      o1.u[jj] = tile[(s0 + 8 + jj) * 72 + dl];
    }
    unsigned short* dp = vt + (size_t)(by * 64 + dl) * NS + st * 64 + s0;
    *(short8*)dp = o0.v;
    *(short8*)(dp + 8) = o1.v;
  }
}

// ---------------- causal GQA flash attention (swapped-operand, exp2-domain, double-buffered) ----------------
// grid = (36 bh, 32 qtIdx), qt = 31 - qtIdx (longest-first). 4 waves x 16 q-rows.
// LDS tiles XOR-swizzled: physical_byte = logical_byte ^ ((row&7)<<4), row stride 128B.
__global__ __launch_bounds__(256)
void k_attn(const unsigned short* __restrict__ qkv,
            const unsigned short* __restrict__ vt,
            unsigned short* __restrict__ ao) {
  __shared__ unsigned short kv_s[2][2][4096];   // [half][K=0/V=1][64 rows x 64]
  __shared__ unsigned short p_s[4][1024];       // per-wave P^T [16 q][64 kv]
  const int tid = threadIdx.x;
  const int w = tid >> 6, l = tid & 63, g = l >> 4, c = l & 15;
  const int bh = blockIdx.x;
  const int qt = 31 - (int)blockIdx.y;
  const int b = bh / NHEADS, h = bh - b * NHEADS, kh = h / NGRP;

  const char* kgb = (const char*)(qkv + (size_t)b * NS * NQKV + NHEADS * NHD + kh * NHD);
  const char* vgb = (const char*)(vt + (size_t)(b * NKVH + kh) * NHD * NS);

  const int lr = l >> 3;                     // 0..7
  const int swz = ((l & 7) ^ lr) << 4;       // pre-swizzled source column byte
  const int r0 = 16 * w + lr;                // this lane's staging row (and +8)
  const int cs = (c & 7) << 4;               // read-side XOR key

  // Q fragments (B-operand): lane holds Q[q=w*16+c][d = dc*32 + g*8 + j], pre-scaled by log2e/8
  const size_t qrow = (size_t)(b * NS + qt * 64 + w * 16 + c) * NQKV + h * NHD;
  const short8 qf0 = *(const short8*)(qkv + qrow + g * 8);
  const short8 qf1 = *(const short8*)(qkv + qrow + 32 + g * 8);

  const short8 ones = {0x3F80, 0x3F80, 0x3F80, 0x3F80, 0x3F80, 0x3F80, 0x3F80, 0x3F80};

  f32x4 ot[4] = {};            // O^T: lane holds O^T[d=nt*16+4g+i][q=w*16+c]
  f32x4 lacc = {};             // row-sum accumulator via mfma(ones, P)
  float m = -1e30f;
  const int q_g = qt * 64 + w * 16 + c;

#define STAGE(j, half)                                                          \
  {                                                                             \
    unsigned short* kl_ = kv_s[half][0];                                        \
    unsigned short* vl_ = kv_s[half][1];                                        \
    gload16(kgb + (size_t)((j) * 64 + r0) * (NQKV * 2) + swz, kl_ + 16 * w * 64);       \
    gload16(kgb + (size_t)((j) * 64 + r0 + 8) * (NQKV * 2) + swz, kl_ + (16 * w + 8) * 64); \
    gload16(vgb + (size_t)r0 * (NS * 2) + (j) * 128 + swz, vl_ + 16 * w * 64);          \
    gload16(vgb + (size_t)(r0 + 8) * (NS * 2) + (j) * 128 + swz, vl_ + (16 * w + 8) * 64); \
  }

  STAGE(0, 0);

  for (int j = 0; j <= qt; ++j) {
    __syncthreads();                     // drains tile-j loads
    if (j < qt) STAGE(j + 1, (j + 1) & 1);
    const char* kl = (const char*)kv_s[j & 1][0];
    const char* vl = (const char*)kv_s[j & 1][1];

    // S^T = K Q^T (log2-domain): lane holds S^T[kv=j*64+nt*16+4g+i][q=c]
    f32x4 st[4] = {};
#pragma unroll
    for (int dc = 0; dc < 2; ++dc) {
      const int col = (dc * 64 + g * 16) ^ cs;
      const short8 qf = dc ? qf1 : qf0;
#pragma unroll
      for (int nt = 0; nt < 4; ++nt) {
        short8 kf = *(const short8*)(kl + (nt * 16 + c) * 128 + col);
        st[nt] = mfma16(kf, qf, st[nt]);
      }
    }

    // causal mask: only the diagonal tile straddles
    if (j == qt) {
#pragma unroll
      for (int nt = 0; nt < 4; ++nt)
#pragma unroll
        for (int i = 0; i < 4; ++i) {
          const int kvg = j * 64 + nt * 16 + 4 * g + i;
          if (kvg > q_g) st[nt][i] = -1e30f;
        }
    }

    // tile max (per lane = one q column): max3-friendly tree + 2 shfl
    float m0 = fmaxf(fmaxf(st[0][0], st[0][1]), st[0][2]);
    float m1 = fmaxf(fmaxf(st[0][3], st[1][0]), st[1][1]);
    float m2 = fmaxf(fmaxf(st[1][2], st[1][3]), st[2][0]);
    float m3 = fmaxf(fmaxf(st[2][1], st[2][2]), st[2][3]);
    float m4 = fmaxf(fmaxf(st[3][0], st[3][1]), st[3][2]);
    float pm = fmaxf(fmaxf(fmaxf(m0, m1), fmaxf(m2, m3)), fmaxf(m4, st[3][3]));
    pm = fmaxf(pm, __shfl_xor(pm, 16));
    pm = fmaxf(pm, __shfl_xor(pm, 32));

    // defer-max (T13): only rescale when tile max grows past threshold (log2 units)
    if (!__all(pm <= m + 8.0f)) {
      const float scl = exp2f(m - pm);
      m = pm;
      lacc *= scl;
#pragma unroll
      for (int nt = 0; nt < 4; ++nt) ot[nt] *= scl;
    }

    // P = exp2(S - m); pack to bf16 (v_cvt_pk) and write P^T rows to per-wave LDS
    {
      char* pw = (char*)p_s[w];
#pragma unroll
      for (int nt = 0; nt < 4; ++nt) {
        float p0 = exp2f(st[nt][0] - m);
        float p1 = exp2f(st[nt][1] - m);
        float p2 = exp2f(st[nt][2] - m);
        float p3 = exp2f(st[nt][3] - m);
        uint32x2 pk;
        pk.x = pk2bf(p0, p1);
        pk.y = pk2bf(p2, p3);
        *(uint32x2*)(pw + c * 128 + ((nt * 32 + g * 8) ^ cs)) = pk;
      }
      // O^T += V^T P^T ; lacc += ones * P^T (row-sums via matrix pipe)
#pragma unroll
      for (int dc = 0; dc < 2; ++dc) {
        const int col = (dc * 64 + g * 16) ^ cs;
        short8 pf = *(const short8*)(pw + c * 128 + col);
        lacc = mfma16(ones, pf, lacc);
#pragma unroll
        for (int nt = 0; nt < 4; ++nt) {
          short8 vf = *(const short8*)(vl + (nt * 16 + c) * 128 + col);
          ot[nt] = mfma16(vf, pf, ot[nt]);
        }
      }
    }
  }

  // O^T -> LDS (swizzled) -> coalesced global write
  __syncthreads();
  {
    char* ol = (char*)kv_s[0][0];
    const float inv = __builtin_amdgcn_rcpf(lacc[0]);
#pragma unroll
    for (int nt = 0; nt < 4; ++nt) {
      uint32x2 pk;
      pk.x = pk2bf(ot[nt][0] * inv, ot[nt][1] * inv);
      pk.y = pk2bf(ot[nt][2] * inv, ot[nt][3] * inv);
      *(uint32x2*)(ol + (w * 16 + c) * 128 + ((nt * 32 + g * 8) ^ cs)) = pk;
    }
  }
  __syncthreads();
  {
    const char* ol = (const char*)kv_s[0][0];
    const int rr = tid >> 2, cb = tid & 3;
    const int rk = (rr & 7) << 4;
    short8 v0 = *(const short8*)(ol + rr * 128 + ((cb * 32) ^ rk));
    short8 v1 = *(const short8*)(ol + rr * 128 + ((cb * 32 + 16) ^ rk));
    char* aop = (char*)(ao + (size_t)(b * NS + qt * 64 + rr) * (NHEADS * NHD) + h * NHD + cb * 16);
    *(short8*)aop = v0;
    *(short8*)(aop + 16) = v1;
  }
#undef STAGE
}

extern "C" void kernel_launch(void* const* d_in, const int* in_sizes, int n_in,
                              void* d_out, int out_size, void* d_ws, size_t ws_size,
                              hipStream_t stream) {
  const float* x = (const float*)d_in[0];
  const float* cosT = (const float*)d_in[1];
  const float* sinT = (const float*)d_in[2];
  const float* Wq = (const float*)d_in[4];
  const float* Wk = (const float*)d_in[5];
  const float* Wv = (const float*)d_in[6];
  const float* Wo = (const float*)d_in[7];

  unsigned short* xb = (unsigned short*)d_ws;                      // [8192][576]
  unsigned short* wqkvT = xb + (size_t)NM * NHID;                  // [960][576]
  unsigned short* woT = wqkvT + (size_t)NQKV * NHID;               // [576][576]
  unsigned short* qkv = woT + (size_t)NHID * NHID;                 // [8192][960]
  unsigned short* vt = qkv + (size_t)NM * NQKV;                    // [12][64][2048]
  unsigned short* ao = vt + (size_t)NB * NKVH * NHD * NS;          // [8192][576]

  k_cvt<<<dim3((NM * NHID / 8 + 255) / 256), 256, 0, stream>>>(x, xb, NM * NHID / 8);
  k_transpose_cvt<<<dim3(9, 9), 256, 0, stream>>>(Wq, wqkvT, NHID, NHID);
  k_transpose_cvt<<<dim3(3, 9), 256, 0, stream>>>(Wk, wqkvT + (size_t)576 * 576, NHID, 192);
  k_transpose_cvt<<<dim3(3, 9), 256, 0, stream>>>(Wv, wqkvT + (size_t)768 * 576, NHID, 192);
  k_transpose_cvt<<<dim3(9, 9), 256, 0, stream>>>(Wo, woT, NHID, NHID);
  k_gemm_bt<0><<<dim3(NQKV / 64, NM / 128), 256, 0, stream>>>(xb, wqkvT, (void*)qkv, NM, NQKV, NHID);
  k_rope<<<dim3(NM * 48 / 256), 256, 0, stream>>>(qkv, cosT, sinT);
  k_vt<<<dim3(NS / 64, NB * NKVH), 256, 0, stream>>>(qkv, vt);
  k_attn<<<dim3(NB * NHEADS, NS / 64), 256, 0, stream>>>(qkv, vt, ao);
  k_gemm_bt<1><<<dim3(NHID / 64, NM / 128), 256, 0, stream>>>(ao, woT, d_out, NM, NHID, NHID);
}